// Round 2
// baseline (338.967 us; speedup 1.0000x reference)
//
#include <hip/hip_runtime.h>

// Spiking eLIF layer: x (B=64, C=512, T=1024) f32, beta scalar, vth (C,).
// Recurrence per (b,c) row over t:
//   rst = spk * vth
//   mem = mem*beta + x[t] - rst        (each op rounded separately, fp32)
//   u   = mem - vth
//   spk = (u > 0) ? 1 : 0
// Output spk per t, layout (B, C, T) — per-row contiguous.
//
// One thread per row (32768 threads = 512 waves, 2/CU). Streaming with
// double-buffered 32-float chunks (8 x 16B vectors), nontemporal loads/stores.
// __f*_rn intrinsics forbid FMA contraction so rounding matches the numpy
// fp32 reference bit-exactly (a flipped spike = 1.0 error and corrupts the
// rest of the sequence via the reset term).

typedef float f32x4 __attribute__((ext_vector_type(4)));

#define T_LEN 1024
#define C_LEN 512
#define CHUNK 32            // floats per chunk per thread
#define VPC   (CHUNK / 4)   // vectors per chunk = 8
#define NCHUNK (T_LEN / CHUNK) // 32

#define STEP(xv, sv)                                   \
    do {                                               \
        float m1_ = __fmul_rn(mem, beta);              \
        float m2_ = __fadd_rn(m1_, (xv));              \
        mem = __fsub_rn(m2_, rst);                     \
        float u_ = __fsub_rn(mem, vth);                \
        bool b_ = (u_ > 0.0f);                         \
        (sv) = b_ ? 1.0f : 0.0f;                       \
        rst = b_ ? vth : 0.0f;                         \
    } while (0)

#define LOADCH(dst, ch)                                                 \
    do {                                                                \
        _Pragma("unroll")                                               \
        for (int i_ = 0; i_ < VPC; ++i_)                                \
            dst[i_] = __builtin_nontemporal_load(xr + (ch) * VPC + i_); \
    } while (0)

#define COMPCH(src, ch)                                              \
    do {                                                             \
        _Pragma("unroll")                                            \
        for (int i_ = 0; i_ < VPC; ++i_) {                           \
            f32x4 v_ = src[i_];                                      \
            f32x4 s_;                                                \
            STEP(v_.x, s_.x);                                        \
            STEP(v_.y, s_.y);                                        \
            STEP(v_.z, s_.z);                                        \
            STEP(v_.w, s_.w);                                        \
            __builtin_nontemporal_store(s_, orow + (ch) * VPC + i_); \
        }                                                            \
    } while (0)

__global__ __launch_bounds__(64) void elif_scan_kernel(
    const float* __restrict__ x,
    const float* __restrict__ beta_p,
    const float* __restrict__ vth_p,
    float* __restrict__ out,
    int n_rows)
{
    const int row = blockIdx.x * 64 + threadIdx.x;
    if (row >= n_rows) return;

    const float beta = beta_p[0];
    const float vth  = vth_p[row & (C_LEN - 1)];

    const f32x4* __restrict__ xr   = reinterpret_cast<const f32x4*>(x   + (size_t)row * T_LEN);
    f32x4* __restrict__       orow = reinterpret_cast<f32x4*>(out + (size_t)row * T_LEN);

    f32x4 bufA[VPC];
    f32x4 bufB[VPC];

    float mem = 0.0f;
    float rst = 0.0f;

    LOADCH(bufA, 0);

    #pragma unroll 1
    for (int ch = 0; ch < NCHUNK; ch += 2) {
        // prefetch chunk ch+1 while computing chunk ch
        LOADCH(bufB, ch + 1);          // ch+1 <= 31 < NCHUNK always (NCHUNK even)
        COMPCH(bufA, ch);
        if (ch + 2 < NCHUNK)
            LOADCH(bufA, ch + 2);
        COMPCH(bufB, ch + 1);
    }
}

extern "C" void kernel_launch(void* const* d_in, const int* in_sizes, int n_in,
                              void* d_out, int out_size, void* d_ws, size_t ws_size,
                              hipStream_t stream) {
    const float* x      = (const float*)d_in[0];
    const float* beta_p = (const float*)d_in[1];
    const float* vth_p  = (const float*)d_in[2];
    float* out          = (float*)d_out;

    const int n_rows = in_sizes[0] / T_LEN;        // B*C = 32768
    const int block  = 64;
    const int grid   = (n_rows + block - 1) / block; // 512 blocks -> 2 per CU

    elif_scan_kernel<<<grid, block, 0, stream>>>(x, beta_p, vth_p, out, n_rows);
}

// Round 3
// 64.250 us; speedup vs baseline: 5.2757x; 5.2757x over previous
//
#include <hip/hip_runtime.h>

// Spiking eLIF layer: x (B=64, C=512, T=1024) f32, beta scalar, vth (C,).
// Recurrence per (b,c) row over t:
//   rst = spk * vth
//   mem = mem*beta + x[t] - rst        (each op rounded separately, fp32)
//   u   = mem - vth
//   spk = (u > 0) ? 1 : 0
// Output spk per t, layout (B, C, T) — per-row contiguous.
//
// One thread per row (32768 threads = 512 waves, 2/CU — structural occupancy
// cap; the scan over T is sequential). Streaming, double-buffered 64-float
// chunks (16 x 16B vectors per buffer). R2 lesson: nontemporal stores caused
// 2.85x write amplification (WRITE_SIZE 365MB vs 128MB) and serialized every
// chunk on HBM-latency store retirement (VALUBusy 0.8%). Plain cached
// loads/stores: L2 coalesces each lane's contiguous 256B/chunk into full
// lines, and vmcnt drains at L2 speed.
//
// __f*_rn intrinsics forbid FMA contraction so rounding matches the numpy
// fp32 reference bit-exactly (a flipped spike = 1.0 error and corrupts the
// rest of the sequence via the reset term).

typedef float f32x4 __attribute__((ext_vector_type(4)));

#define T_LEN 1024
#define C_LEN 512
#define CHUNK 64            // floats per chunk per thread
#define VPC   (CHUNK / 4)   // vectors per chunk = 16
#define NCHUNK (T_LEN / CHUNK) // 16

#define STEP(xv, sv)                                   \
    do {                                               \
        float m1_ = __fmul_rn(mem, beta);              \
        float m2_ = __fadd_rn(m1_, (xv));              \
        mem = __fsub_rn(m2_, rst);                     \
        float u_ = __fsub_rn(mem, vth);                \
        bool b_ = (u_ > 0.0f);                         \
        (sv) = b_ ? 1.0f : 0.0f;                       \
        rst = b_ ? vth : 0.0f;                         \
    } while (0)

#define LOADCH(dst, ch)                                  \
    do {                                                 \
        _Pragma("unroll")                                \
        for (int i_ = 0; i_ < VPC; ++i_)                 \
            dst[i_] = xr[(ch) * VPC + i_];               \
    } while (0)

#define COMPCH(src, ch)                                  \
    do {                                                 \
        _Pragma("unroll")                                \
        for (int i_ = 0; i_ < VPC; ++i_) {               \
            f32x4 v_ = src[i_];                          \
            f32x4 s_;                                    \
            STEP(v_.x, s_.x);                            \
            STEP(v_.y, s_.y);                            \
            STEP(v_.z, s_.z);                            \
            STEP(v_.w, s_.w);                            \
            orow[(ch) * VPC + i_] = s_;                  \
        }                                                \
    } while (0)

__global__ __launch_bounds__(64) void elif_scan_kernel(
    const float* __restrict__ x,
    const float* __restrict__ beta_p,
    const float* __restrict__ vth_p,
    float* __restrict__ out,
    int n_rows)
{
    const int row = blockIdx.x * 64 + threadIdx.x;
    if (row >= n_rows) return;

    const float beta = beta_p[0];
    const float vth  = vth_p[row & (C_LEN - 1)];

    const f32x4* __restrict__ xr   = reinterpret_cast<const f32x4*>(x   + (size_t)row * T_LEN);
    f32x4* __restrict__       orow = reinterpret_cast<f32x4*>(out + (size_t)row * T_LEN);

    f32x4 bufA[VPC];
    f32x4 bufB[VPC];

    float mem = 0.0f;
    float rst = 0.0f;

    LOADCH(bufA, 0);

    #pragma unroll 1
    for (int ch = 0; ch < NCHUNK; ch += 2) {
        // prefetch chunk ch+1 while computing chunk ch
        LOADCH(bufB, ch + 1);          // ch+1 <= 15 < NCHUNK always (NCHUNK even)
        COMPCH(bufA, ch);
        if (ch + 2 < NCHUNK)
            LOADCH(bufA, ch + 2);
        COMPCH(bufB, ch + 1);
    }
}

extern "C" void kernel_launch(void* const* d_in, const int* in_sizes, int n_in,
                              void* d_out, int out_size, void* d_ws, size_t ws_size,
                              hipStream_t stream) {
    const float* x      = (const float*)d_in[0];
    const float* beta_p = (const float*)d_in[1];
    const float* vth_p  = (const float*)d_in[2];
    float* out          = (float*)d_out;

    const int n_rows = in_sizes[0] / T_LEN;        // B*C = 32768
    const int block  = 64;
    const int grid   = (n_rows + block - 1) / block; // 512 blocks -> 2 per CU

    elif_scan_kernel<<<grid, block, 0, stream>>>(x, beta_p, vth_p, out, n_rows);
}

// Round 4
// 60.351 us; speedup vs baseline: 5.6166x; 1.0646x over previous
//
#include <hip/hip_runtime.h>

// Spiking eLIF layer: x (B=64, C=512, T=1024) f32, beta scalar, vth (C,).
// Recurrence per (b,c) row over t:
//   rst = spk * vth
//   mem = mem*beta + x[t] - rst        (each op rounded separately, fp32)
//   spk = (mem - vth > 0) ? 1 : 0      == (mem > vth) in IEEE RN (see note)
// Output spk per t, layout (B, C, T) — per-row contiguous.
//
// One thread per row (32768 threads = 512 waves, 2/CU — structural occupancy
// cap; the scan over T is sequential). R3 showed 1-deep prefetch leaves us
// latency-bound at ~4 TB/s (VALUBusy 4%): queue-inflated load latency ~2us
// needs ~12.6MB in flight (Little's law), 1-deep gives ~8MB. This version:
// 3-deep prefetch, 4 named register buffers x 64-float chunks (768B/lane in
// flight, ~25MB aggregate). NCHUNK=16 = 4 stages x 4 iterations, no tail.
//
// Correctness notes:
// - __f*_rn intrinsics forbid FMA contraction so rounding matches the numpy
//   fp32 reference bit-exactly (a flipped spike = 1.0 error and corrupts the
//   rest of the sequence via the reset term).
// - (fl(mem-vth) > 0) <=> (mem > vth): round-to-nearest preserves sign and,
//   with gradual underflow, fl(a-b)==0 iff a==b (subnormal differences of
//   fp32 values are exact). So the explicit subtract is dropped.

typedef float f32x4 __attribute__((ext_vector_type(4)));

#define T_LEN 1024
#define C_LEN 512
#define CHUNK 64            // floats per chunk per thread
#define VPC   (CHUNK / 4)   // vectors per chunk = 16
#define NCHUNK (T_LEN / CHUNK) // 16

#define STEP(xv, sv)                                   \
    do {                                               \
        float m1_ = __fmul_rn(mem, beta);              \
        float m2_ = __fadd_rn(m1_, (xv));              \
        mem = __fsub_rn(m2_, rst);                     \
        bool b_ = (mem > vth);                         \
        (sv) = b_ ? 1.0f : 0.0f;                       \
        rst = b_ ? vth : 0.0f;                         \
    } while (0)

#define LOADCH(dst, ch)                                  \
    do {                                                 \
        _Pragma("unroll")                                \
        for (int i_ = 0; i_ < VPC; ++i_)                 \
            dst[i_] = xr[(ch) * VPC + i_];               \
    } while (0)

#define COMPCH(src, ch)                                  \
    do {                                                 \
        _Pragma("unroll")                                \
        for (int i_ = 0; i_ < VPC; ++i_) {               \
            f32x4 v_ = src[i_];                          \
            f32x4 s_;                                    \
            STEP(v_.x, s_.x);                            \
            STEP(v_.y, s_.y);                            \
            STEP(v_.z, s_.z);                            \
            STEP(v_.w, s_.w);                            \
            orow[(ch) * VPC + i_] = s_;                  \
        }                                                \
    } while (0)

__global__ __launch_bounds__(64, 1) void elif_scan_kernel(
    const float* __restrict__ x,
    const float* __restrict__ beta_p,
    const float* __restrict__ vth_p,
    float* __restrict__ out,
    int n_rows)
{
    const int row = blockIdx.x * 64 + threadIdx.x;
    if (row >= n_rows) return;

    const float beta = beta_p[0];
    const float vth  = vth_p[row & (C_LEN - 1)];

    const f32x4* __restrict__ xr   = reinterpret_cast<const f32x4*>(x   + (size_t)row * T_LEN);
    f32x4* __restrict__       orow = reinterpret_cast<f32x4*>(out + (size_t)row * T_LEN);

    f32x4 bufA[VPC];
    f32x4 bufB[VPC];
    f32x4 bufC[VPC];
    f32x4 bufD[VPC];

    float mem = 0.0f;
    float rst = 0.0f;

    // prologue: 3 chunks in flight
    LOADCH(bufA, 0);
    LOADCH(bufB, 1);
    LOADCH(bufC, 2);

    // 4 stages per iteration, 4 iterations == NCHUNK=16 chunks, no tail.
    // When COMP(X, k) starts, loads for k+1, k+2, k+3 are in flight (3-deep).
    #pragma unroll 1
    for (int ch = 0; ch < NCHUNK; ch += 4) {
        LOADCH(bufD, ch + 3);                        // ch+3 <= 15 always
        COMPCH(bufA, ch);
        if (ch + 4 < NCHUNK) LOADCH(bufA, ch + 4);
        COMPCH(bufB, ch + 1);
        if (ch + 5 < NCHUNK) LOADCH(bufB, ch + 5);
        COMPCH(bufC, ch + 2);
        if (ch + 6 < NCHUNK) LOADCH(bufC, ch + 6);
        COMPCH(bufD, ch + 3);
    }
}

extern "C" void kernel_launch(void* const* d_in, const int* in_sizes, int n_in,
                              void* d_out, int out_size, void* d_ws, size_t ws_size,
                              hipStream_t stream) {
    const float* x      = (const float*)d_in[0];
    const float* beta_p = (const float*)d_in[1];
    const float* vth_p  = (const float*)d_in[2];
    float* out          = (float*)d_out;

    const int n_rows = in_sizes[0] / T_LEN;        // B*C = 32768
    const int block  = 64;
    const int grid   = (n_rows + block - 1) / block; // 512 blocks -> 2 per CU

    elif_scan_kernel<<<grid, block, 0, stream>>>(x, beta_p, vth_p, out, n_rows);
}

// Round 5
// 59.876 us; speedup vs baseline: 5.6611x; 1.0079x over previous
//
#include <hip/hip_runtime.h>

// Spiking eLIF layer: x (B=64, C=512, T=1024) f32, beta scalar, vth (C,).
// Recurrence per (b,c) row over t:
//   rst = spk * vth
//   mem = mem*beta + x[t] - rst        (each op rounded separately, fp32)
//   spk = (mem > vth) ? 1 : 0          (== (mem - vth > 0) in IEEE RN)
// Output spk per t, layout (B, C, T) — per-row contiguous.
//
// One thread per row (32768 threads = 512 waves, 2/CU — structural cap; the
// T-scan is sequential). Latency-bound regime: VALUBusy ~4%, BW ~2.2 TB/s.
// R4 lesson: a source-level 3-deep prefetch got silently collapsed by the
// scheduler (VGPR=140 < the 192+ three live chunks require — loads were
// re-sunk to their consumers). This version pins the pipeline with
// __builtin_amdgcn_sched_barrier(0) after every load block: loads cannot
// sink, compute cannot hoist. Expect VGPR ~250 (fine at launch_bounds(64,1),
// occupancy already 1 wave/SIMD).
//
// Correctness notes:
// - __f*_rn intrinsics forbid FMA contraction so rounding matches the numpy
//   fp32 reference bit-exactly (a flipped spike = 1.0 error and corrupts the
//   rest of the sequence via the reset term).
// - (fl(mem-vth) > 0) <=> (mem > vth): RN preserves sign; with gradual
//   underflow fl(a-b)==0 iff a==b. So the explicit subtract is dropped.

typedef float f32x4 __attribute__((ext_vector_type(4)));

#define T_LEN 1024
#define C_LEN 512
#define CHUNK 64            // floats per chunk per thread
#define VPC   (CHUNK / 4)   // vectors per chunk = 16
#define NCHUNK (T_LEN / CHUNK) // 16

#define SB() __builtin_amdgcn_sched_barrier(0)

#define STEP(xv, sv)                                   \
    do {                                               \
        float m1_ = __fmul_rn(mem, beta);              \
        float m2_ = __fadd_rn(m1_, (xv));              \
        mem = __fsub_rn(m2_, rst);                     \
        bool b_ = (mem > vth);                         \
        (sv) = b_ ? 1.0f : 0.0f;                       \
        rst = b_ ? vth : 0.0f;                         \
    } while (0)

#define LOADCH(dst, ch)                                  \
    do {                                                 \
        _Pragma("unroll")                                \
        for (int i_ = 0; i_ < VPC; ++i_)                 \
            dst[i_] = xr[(ch) * VPC + i_];               \
    } while (0)

#define COMPCH(src, ch)                                  \
    do {                                                 \
        _Pragma("unroll")                                \
        for (int i_ = 0; i_ < VPC; ++i_) {               \
            f32x4 v_ = src[i_];                          \
            f32x4 s_;                                    \
            STEP(v_.x, s_.x);                            \
            STEP(v_.y, s_.y);                            \
            STEP(v_.z, s_.z);                            \
            STEP(v_.w, s_.w);                            \
            orow[(ch) * VPC + i_] = s_;                  \
        }                                                \
    } while (0)

__global__ __launch_bounds__(64, 1) void elif_scan_kernel(
    const float* __restrict__ x,
    const float* __restrict__ beta_p,
    const float* __restrict__ vth_p,
    float* __restrict__ out,
    int n_rows)
{
    const int row = blockIdx.x * 64 + threadIdx.x;
    if (row >= n_rows) return;

    const float beta = beta_p[0];
    const float vth  = vth_p[row & (C_LEN - 1)];

    const f32x4* __restrict__ xr   = reinterpret_cast<const f32x4*>(x   + (size_t)row * T_LEN);
    f32x4* __restrict__       orow = reinterpret_cast<f32x4*>(out + (size_t)row * T_LEN);

    f32x4 bufA[VPC];
    f32x4 bufB[VPC];
    f32x4 bufC[VPC];
    f32x4 bufD[VPC];

    float mem = 0.0f;
    float rst = 0.0f;

    // prologue: 3 chunks in flight, order pinned
    LOADCH(bufA, 0);
    SB();
    LOADCH(bufB, 1);
    SB();
    LOADCH(bufC, 2);
    SB();

    // 4 stages per iteration, 4 iterations == NCHUNK=16 chunks, no tail.
    // When COMPCH(X, k) starts, loads for k+1, k+2, k+3 have been ISSUED
    // (pinned by sched_barrier(0) — loads cannot sink past it, compute
    // cannot hoist above it).
    #pragma unroll 1
    for (int ch = 0; ch < NCHUNK; ch += 4) {
        LOADCH(bufD, ch + 3);                        // ch+3 <= 15 always
        SB();
        COMPCH(bufA, ch);
        SB();
        if (ch + 4 < NCHUNK) LOADCH(bufA, ch + 4);
        SB();
        COMPCH(bufB, ch + 1);
        SB();
        if (ch + 5 < NCHUNK) LOADCH(bufB, ch + 5);
        SB();
        COMPCH(bufC, ch + 2);
        SB();
        if (ch + 6 < NCHUNK) LOADCH(bufC, ch + 6);
        SB();
        COMPCH(bufD, ch + 3);
        SB();
    }
}

extern "C" void kernel_launch(void* const* d_in, const int* in_sizes, int n_in,
                              void* d_out, int out_size, void* d_ws, size_t ws_size,
                              hipStream_t stream) {
    const float* x      = (const float*)d_in[0];
    const float* beta_p = (const float*)d_in[1];
    const float* vth_p  = (const float*)d_in[2];
    float* out          = (float*)d_out;

    const int n_rows = in_sizes[0] / T_LEN;        // B*C = 32768
    const int block  = 64;
    const int grid   = (n_rows + block - 1) / block; // 512 blocks -> 2 per CU

    elif_scan_kernel<<<grid, block, 0, stream>>>(x, beta_p, vth_p, out, n_rows);
}

// Round 6
// 47.318 us; speedup vs baseline: 7.1636x; 1.2654x over previous
//
#include <hip/hip_runtime.h>

// Spiking eLIF layer: x (B=64, C=512, T=1024) f32, beta scalar, vth (C,).
//   rst = spk*vth; mem = mem*beta + x[t] - rst; spk = (mem > vth) ? 1 : 0
// Output spk, layout (B, C, T).
//
// R5 post-mortem: register-prefetch depth is compiler-defeated (VGPR pinned
// at 140 across R4/R5; sched_barrier(0) is IR-transparent for pure loads).
// Real bottleneck: address divergence — 1 lane per row means every wave
// memory instruction touches 64 lines at 4KB stride (TA request-rate
// collapse, ~2.2 TB/s = L2/16 signature).
//
// This version: LDS-transpose staging, fully coalesced global access.
//  - 1 wave per block = 64 consecutive rows.
//  - chunk = 64 floats/row; 16 load instrs each cover 4 rows x 256B
//    contiguous (16 contiguous lanes per row) -> 4 segments/instr vs 64.
//  - XOR swizzle (T2, pcol = j ^ (row&15)) applied by pre-swizzling the
//    GLOBAL address; LDS writes stay lane-linear, per-row LDS reads are
//    bank-conflict-free (phase (j&7)^(l&7), uniform).
//  - spikes transposed back through out_lds, coalesced stores.
//  - single wave => no __syncthreads, no vmcnt(0) barrier drain; LDS deps
//    are same-wave and compiler-ordered via lgkmcnt.
//
// Correctness: __f*_rn forbids FMA contraction (bit-exact vs numpy fp32;
// one flipped spike corrupts the rest of the row via reset). (mem > vth)
// == (fl(mem-vth) > 0) in IEEE RN with gradual underflow.

typedef float f32x4 __attribute__((ext_vector_type(4)));

#define T_LEN   1024
#define C_LEN   512
#define RPB     64                // rows per block (= lanes per wave)
#define CHUNK   64                // t-steps per slab
#define VECS    16                // f32x4 per row per slab
#define NCH     (T_LEN / CHUNK)   // 16 slabs
#define ROWV    (T_LEN / 4)       // row stride in f32x4 = 256

#define STEP(xv_, sv_)                                 \
    do {                                               \
        float m1_ = __fmul_rn(mem, beta);              \
        float m2_ = __fadd_rn(m1_, (xv_));             \
        mem = __fsub_rn(m2_, rst);                     \
        bool b_ = (mem > vth);                         \
        (sv_) = b_ ? 1.0f : 0.0f;                      \
        rst = b_ ? vth : 0.0f;                         \
    } while (0)

// 16 coalesced loads: instr j covers rows 4j..4j+3, 16 contiguous lanes per
// row; global col is pre-swizzled so LDS write below is lane-linear.
#define LOADS(ch)                                                         \
    do {                                                                  \
        _Pragma("unroll")                                                 \
        for (int j_ = 0; j_ < VECS; ++j_) {                               \
            const int rj_ = 4 * j_ + l4;                                  \
            const int gc_ = c16 ^ (rj_ & 15);                             \
            stg[j_] = xv[(size_t)(rb + rj_) * ROWV + (ch) * VECS + gc_];  \
        }                                                                 \
    } while (0)

// lane-linear LDS write: slot 64j + l == [row rj][pcol c16]
#define DSW(buf)                                                          \
    do {                                                                  \
        _Pragma("unroll")                                                 \
        for (int j_ = 0; j_ < VECS; ++j_)                                 \
            in_lds[buf][64 * j_ + l] = stg[j_];                           \
    } while (0)

// lane l scans its own row l: logical col j at physical slot l*16+(j^c16)
#define COMPUTE(buf)                                                      \
    do {                                                                  \
        _Pragma("unroll")                                                 \
        for (int j_ = 0; j_ < VECS; ++j_) {                               \
            f32x4 v_ = in_lds[buf][l * VECS + (j_ ^ c16)];                \
            f32x4 s_;                                                     \
            STEP(v_.x, s_.x);                                             \
            STEP(v_.y, s_.y);                                             \
            STEP(v_.z, s_.z);                                             \
            STEP(v_.w, s_.w);                                             \
            out_lds[l * VECS + (j_ ^ c16)] = s_;                          \
        }                                                                 \
    } while (0)

// mirror of LOADS: lane-linear LDS read, coalesced (pre-swizzled) store
#define DRAIN(ch)                                                         \
    do {                                                                  \
        _Pragma("unroll")                                                 \
        for (int j_ = 0; j_ < VECS; ++j_) {                               \
            const int rj_ = 4 * j_ + l4;                                  \
            const int gc_ = c16 ^ (rj_ & 15);                             \
            ov[(size_t)(rb + rj_) * ROWV + (ch) * VECS + gc_] =           \
                out_lds[64 * j_ + l];                                     \
        }                                                                 \
    } while (0)

__global__ __launch_bounds__(64, 1) void elif_scan_kernel(
    const float* __restrict__ x,
    const float* __restrict__ beta_p,
    const float* __restrict__ vth_p,
    float* __restrict__ out)
{
    __shared__ f32x4 in_lds[2][RPB * VECS];   // 2 x 16 KB, double-buffered
    __shared__ f32x4 out_lds[RPB * VECS];     // 16 KB

    const int l   = threadIdx.x;   // lane 0..63
    const int l4  = l >> 4;        // 0..3
    const int c16 = l & 15;        // 0..15
    const int rb  = blockIdx.x * RPB;

    const f32x4* __restrict__ xv = (const f32x4*)x;
    f32x4* __restrict__       ov = (f32x4*)out;

    const float beta = beta_p[0];
    const float vth  = vth_p[(rb + l) & (C_LEN - 1)];

    f32x4 stg[VECS];               // staged slab (compile-time indexed only)
    float mem = 0.0f;
    float rst = 0.0f;

    // prologue: slab 0 into in_lds[0]; slab 1 loads in flight
    LOADS(0);
    DSW(0);
    LOADS(1);

    #pragma unroll 1
    for (int ch = 0; ch < NCH; ++ch) {
        // invariant: in_lds[ch&1] holds slab ch; stg holds slab ch+1 (in flight)
        COMPUTE(ch & 1);
        DRAIN(ch);
        if (ch < NCH - 1) DSW((ch + 1) & 1);   // vmcnt wait hidden under compute+drain
        if (ch < NCH - 2) LOADS(ch + 2);       // issue next slab
    }
}

extern "C" void kernel_launch(void* const* d_in, const int* in_sizes, int n_in,
                              void* d_out, int out_size, void* d_ws, size_t ws_size,
                              hipStream_t stream) {
    const float* x      = (const float*)d_in[0];
    const float* beta_p = (const float*)d_in[1];
    const float* vth_p  = (const float*)d_in[2];
    float* out          = (float*)d_out;

    const int n_rows = in_sizes[0] / T_LEN;      // B*C = 32768
    const int grid   = n_rows / RPB;             // 512 blocks -> 2 per CU

    elif_scan_kernel<<<grid, RPB, 0, stream>>>(x, beta_p, vth_p, out);
}